// Round 8
// baseline (337.229 us; speedup 1.0000x reference)
//
#include <hip/hip_runtime.h>
#include <hip/hip_bf16.h>

typedef unsigned short u16;
typedef short bf16x8 __attribute__((ext_vector_type(8)));
typedef float f32x4 __attribute__((ext_vector_type(4)));

#define NEG_BIG (-1e30f)
#define SCL 0.18033688f   // 0.125 * log2(e): Q pre-scaled so scores are in log2 units

#if __has_builtin(__builtin_amdgcn_exp2f)
#define EXP2(x) __builtin_amdgcn_exp2f(x)
#else
#define EXP2(x) exp2f(x)
#endif

__device__ __forceinline__ u16 f2bf(float f) {
    union { float f; unsigned int u; } x; x.f = f;
    unsigned int r = x.u + 0x7fffu + ((x.u >> 16) & 1u);
    return (u16)(r >> 16);
}

// pack two floats to bf16x2 by truncation: 1 v_perm_b32
__device__ __forceinline__ unsigned int pack_bf2(float a, float b) {
    union { float f; unsigned int u; } ua, ub; ua.f = a; ub.f = b;
    return __builtin_amdgcn_perm(ub.u, ua.u, 0x07060302u);
}

__device__ __forceinline__ void dma16(const u16* g, const u16* lds) {
    __builtin_amdgcn_global_load_lds(
        (const __attribute__((address_space(1))) unsigned int*)g,
        (__attribute__((address_space(3))) unsigned int*)lds, 16, 0, 0);
}

__device__ __forceinline__ bf16x8 sfrag(const u16* lds, int row, int kb8) {
    int slot = row * 8 + (kb8 ^ (row & 7));
    return *(const bf16x8*)(lds + slot * 8);
}

// ---------------- fused fp32 -> bf16 convert ----------------
__global__ __launch_bounds__(256) void cvt_all(const float* __restrict__ x,
                                               const float* __restrict__ wq,
                                               const float* __restrict__ wk,
                                               const float* __restrict__ wv,
                                               const float* __restrict__ wo,
                                               u16* __restrict__ xb, u16* __restrict__ wqb,
                                               u16* __restrict__ wkb, u16* __restrict__ wvb,
                                               u16* __restrict__ wob) {
    size_t i = (size_t)blockIdx.x * 256 + threadIdx.x;
    const float* s; u16* d; size_t off;
    if      (i < 1048576) { s = x;  d = xb;  off = i; }
    else if (i < 1572864) { s = wq; d = wqb; off = i - 1048576; }
    else if (i < 1703936) { s = wk; d = wkb; off = i - 1572864; }
    else if (i < 1835008) { s = wv; d = wvb; off = i - 1703936; }
    else                  { s = wo; d = wob; off = i - 1835008; }
    const float* p = s + off * 8;
    float4 a = *(const float4*)p;
    float4 b = *(const float4*)(p + 4);
    bf16x8 r;
    r[0] = (short)f2bf(a.x); r[1] = (short)f2bf(a.y);
    r[2] = (short)f2bf(a.z); r[3] = (short)f2bf(a.w);
    r[4] = (short)f2bf(b.x); r[5] = (short)f2bf(b.y);
    r[6] = (short)f2bf(b.z); r[7] = (short)f2bf(b.w);
    *(bf16x8*)(d + off * 8) = r;
}

// ---------------- bf16 GEMM (m97-style), fp32 output ----------------
__global__ __launch_bounds__(256) void gemm_bt(const u16* __restrict__ A,
                                               const u16* __restrict__ Bt,
                                               float* __restrict__ C,
                                               int M, int N, int K) {
    __shared__ u16 As[8192];
    __shared__ u16 Bs[8192];
    const int t = threadIdx.x;
    const int wave = t >> 6, lane = t & 63;
    const int wm = (wave >> 1) * 64, wn = (wave & 1) * 64;
    const int lhi = lane >> 4, llo = lane & 15;
    const int m0 = blockIdx.y * 128, n0 = blockIdx.x * 128;
    const int wbase = wave * 64;

    f32x4 acc[4][4] = {};
    for (int k0 = 0; k0 < K; k0 += 64) {
        const u16* Ab = A + (size_t)m0 * K + k0;
        const u16* Bb = Bt + (size_t)n0 * K + k0;
#pragma unroll
        for (int i = 0; i < 4; ++i) {
            int s = i * 256 + t;
            int row = s >> 3, gch = (s & 7) ^ (row & 7);
            dma16(Ab + (size_t)row * K + gch * 8, As + (i * 256 + wbase) * 8);
            dma16(Bb + (size_t)row * K + gch * 8, Bs + (i * 256 + wbase) * 8);
        }
        __syncthreads();
#pragma unroll
        for (int ks = 0; ks < 2; ++ks) {
            const int kb = ks * 4 + lhi;
            bf16x8 af[4], bfg[4];
#pragma unroll
            for (int mi = 0; mi < 4; ++mi) af[mi] = sfrag(As, wm + mi * 16 + llo, kb);
#pragma unroll
            for (int ni = 0; ni < 4; ++ni) bfg[ni] = sfrag(Bs, wn + ni * 16 + llo, kb);
#pragma unroll
            for (int mi = 0; mi < 4; ++mi)
#pragma unroll
                for (int ni = 0; ni < 4; ++ni)
                    acc[mi][ni] = __builtin_amdgcn_mfma_f32_16x16x32_bf16(
                        af[mi], bfg[ni], acc[mi][ni], 0, 0, 0);
        }
        __syncthreads();
    }
#pragma unroll
    for (int mi = 0; mi < 4; ++mi)
#pragma unroll
        for (int ni = 0; ni < 4; ++ni)
#pragma unroll
            for (int r = 0; r < 4; ++r) {
                int row = m0 + wm + mi * 16 + lhi * 4 + r;
                int col = n0 + wn + ni * 16 + llo;
                C[(size_t)row * N + col] = acc[mi][ni][r];
            }
}

// ---------------- merged Q/K/V projection ----------------
// bx 0..15: Q [4096][2048] bf16, PRE-SCALED by SCL | bx 16..19: K | bx 20..23: Vt
__global__ __launch_bounds__(256) void gemm_qkv(const u16* __restrict__ A,
                                                const u16* __restrict__ Wq,
                                                const u16* __restrict__ Wk,
                                                const u16* __restrict__ Wv,
                                                u16* __restrict__ Qout,
                                                u16* __restrict__ Kout,
                                                u16* __restrict__ Vtout) {
    const int K = 2048;
    __shared__ u16 As[8192];
    __shared__ u16 Bs[8192];
    const int t = threadIdx.x;
    const int wave = t >> 6, lane = t & 63;
    const int wm = (wave >> 1) * 64, wn = (wave & 1) * 64;
    const int lhi = lane >> 4, llo = lane & 15;
    const int m0 = blockIdx.y * 128;
    const int bx = blockIdx.x;
    const int kind = (bx < 16) ? 0 : (bx < 20 ? 1 : 2);
    const int n0 = (kind == 0) ? bx * 128 : (bx & 3) * 128;
    const u16* Bt = ((kind == 0) ? Wq : (kind == 1) ? Wk : Wv) + (size_t)n0 * K;
    const int wbase = wave * 64;

    f32x4 acc[4][4] = {};
    for (int k0 = 0; k0 < K; k0 += 64) {
        const u16* Ab = A + (size_t)m0 * K + k0;
        const u16* Bb = Bt + k0;
#pragma unroll
        for (int i = 0; i < 4; ++i) {
            int s = i * 256 + t;
            int row = s >> 3, gch = (s & 7) ^ (row & 7);
            dma16(Ab + (size_t)row * K + gch * 8, As + (i * 256 + wbase) * 8);
            dma16(Bb + (size_t)row * K + gch * 8, Bs + (i * 256 + wbase) * 8);
        }
        __syncthreads();
#pragma unroll
        for (int ks = 0; ks < 2; ++ks) {
            const int kb = ks * 4 + lhi;
            bf16x8 af[4], bfg[4];
#pragma unroll
            for (int mi = 0; mi < 4; ++mi) af[mi] = sfrag(As, wm + mi * 16 + llo, kb);
#pragma unroll
            for (int ni = 0; ni < 4; ++ni) bfg[ni] = sfrag(Bs, wn + ni * 16 + llo, kb);
#pragma unroll
            for (int mi = 0; mi < 4; ++mi)
#pragma unroll
                for (int ni = 0; ni < 4; ++ni)
                    acc[mi][ni] = __builtin_amdgcn_mfma_f32_16x16x32_bf16(
                        af[mi], bfg[ni], acc[mi][ni], 0, 0, 0);
        }
        __syncthreads();
    }

    if (kind == 0) {
#pragma unroll
        for (int mi = 0; mi < 4; ++mi)
#pragma unroll
            for (int ni = 0; ni < 4; ++ni)
#pragma unroll
                for (int r = 0; r < 4; ++r) {
                    int row = m0 + wm + mi * 16 + lhi * 4 + r;
                    int col = n0 + wn + ni * 16 + llo;
                    Qout[(size_t)row * 2048 + col] = f2bf(acc[mi][ni][r] * SCL);
                }
    } else if (kind == 1) {
#pragma unroll
        for (int mi = 0; mi < 4; ++mi)
#pragma unroll
            for (int ni = 0; ni < 4; ++ni)
#pragma unroll
                for (int r = 0; r < 4; ++r) {
                    int row = m0 + wm + mi * 16 + lhi * 4 + r;
                    int col = n0 + wn + ni * 16 + llo;
                    Kout[(size_t)row * 512 + col] = f2bf(acc[mi][ni][r]);
                }
    } else {
        // Vt[b][g][hd][s]: off = (col + (row>>11)*512)*2048 + (row&2047)
#pragma unroll
        for (int mi = 0; mi < 4; ++mi)
#pragma unroll
            for (int ni = 0; ni < 4; ++ni) {
                int row = m0 + wm + mi * 16 + lhi * 4;
                int col = n0 + wn + ni * 16 + llo;
                size_t off = ((size_t)col + (size_t)(row >> 11) * 512) * 2048 + (row & 2047);
                short4 v;
                v.x = (short)f2bf(acc[mi][ni][0]);
                v.y = (short)f2bf(acc[mi][ni][1]);
                v.z = (short)f2bf(acc[mi][ni][2]);
                v.w = (short)f2bf(acc[mi][ni][3]);
                *(short4*)(Vtout + off) = v;
            }
    }
}

// ---------------- flash GQA attention v6: paired q-tiles, lean VALU path ----------------
// grid: x in [0,64), y = b*8+g. Block x handles qt = 127-x then qt = x (33 iters for all x).
__global__ __launch_bounds__(256, 4) void attn6(const u16* __restrict__ Q,
                                                const u16* __restrict__ Kb,
                                                const u16* __restrict__ Vt,
                                                u16* __restrict__ Ctx) {
    __shared__ u16 Ks[4096];        // 64 k-rows x 8 hd-chunks, swizzled (8KB)
    __shared__ u16 Vs[4096];        // 64 hd-rows x 8 s-chunks, swizzled (8KB)
    __shared__ u16 Pl[4][16][72];   // per-wave P[q][s] (9KB)
    const int bg = blockIdx.y;
    const int b = bg >> 3, g = bg & 7;
    const int t = threadIdx.x, w = t >> 6, lane = t & 63;
    const int lhi = lane >> 4, llo = lane & 15;
    const int h = g * 4 + w;
    const int wbase = w * 64;

    const u16* Kp = Kb + (size_t)(b * 2048) * 512 + g * 64;
    const u16* Vp = Vt + (size_t)bg * 64 * 2048;

    // hoisted staging lane geometry
    const int s0 = t, s1 = 256 + t;
    const int r0 = s0 >> 3, c0 = ((s0 & 7) ^ (r0 & 7)) * 8;
    const int r1 = s1 >> 3, c1 = ((s1 & 7) ^ (r1 & 7)) * 8;
    u16* kd0 = (u16*)Ks + (0 * 256 + wbase) * 8;
    u16* kd1 = (u16*)Ks + (1 * 256 + wbase) * 8;
    u16* vd0 = (u16*)Vs + (0 * 256 + wbase) * 8;
    u16* vd1 = (u16*)Vs + (1 * 256 + wbase) * 8;
    // wave-private P base addresses (per-lane constant)
    u16* pw0 = &Pl[w][llo][lhi * 4];

#pragma unroll
    for (int ph = 0; ph < 2; ++ph) {
        const int qt = ph ? (int)blockIdx.x : 127 - (int)blockIdx.x;

        const u16* Qp = Q + ((size_t)(b * 2048 + qt * 16)) * 2048 + h * 64;
        bf16x8 aq[2];
#pragma unroll
        for (int ks = 0; ks < 2; ++ks)
            aq[ks] = *(const bf16x8*)(Qp + (size_t)llo * 2048 + ks * 32 + lhi * 8);

        const u16* k0p = Kp + (size_t)r0 * 512 + c0;
        const u16* k1p = Kp + (size_t)r1 * 512 + c1;
        const u16* v0p = Vp + (size_t)r0 * 2048 + c0;
        const u16* v1p = Vp + (size_t)r1 * 2048 + c1;

        f32x4 o[4] = {};          // O^T: [hd-tile], lane q=llo, hd=hb*16+lhi*4+r
        float m_ = NEG_BIG, l_ = 0.f;

        const int qlast = qt * 16 + 15;        // last valid k for this q-tile
        const int ktmax = qlast >> 6;
        for (int kt = 0; kt <= ktmax; ++kt) {
            __syncthreads();
            dma16(k0p, kd0); dma16(k1p, kd1);
            dma16(v0p, vd0); dma16(v1p, vd1);
            k0p += 64 * 512; k1p += 64 * 512; v0p += 64; v1p += 64;
            __syncthreads();

            // live kb sub-tiles (wave-uniform): kb < kblim
            int kblim = ((qlast - kt * 64) >> 4) + 1;
            kblim = kblim > 4 ? 4 : kblim;

            // S^T = K Q^T : st[kb], D[m=k][n=q] (log2 units; Q pre-scaled)
            f32x4 st[4];
#pragma unroll
            for (int ks = 0; ks < 2; ++ks) {
                const int kb8 = ks * 4 + lhi;
#pragma unroll
                for (int kb = 0; kb < 4; ++kb) {
                    if (kb < kblim) {
                        bf16x8 kf = sfrag(Ks, kb * 16 + llo, kb8);
                        if (ks == 0) st[kb] = (f32x4){0.f, 0.f, 0.f, 0.f};
                        st[kb] = __builtin_amdgcn_mfma_f32_16x16x32_bf16(
                            kf, aq[ks], st[kb], 0, 0, 0);
                    }
                }
            }

            // causal mask (only diagonal tile pays)
            if (kt == ktmax && (kt * 64 + 63) > qt * 16) {
                int qg = qt * 16 + llo;
#pragma unroll
                for (int kb = 0; kb < 4; ++kb)
                    if (kb < kblim)
#pragma unroll
                        for (int r = 0; r < 4; ++r) {
                            int kg = kt * 64 + kb * 16 + lhi * 4 + r;
                            if (kg > qg) st[kb][r] = NEG_BIG;
                        }
            }

            // per-q max: in-lane fmax + 2 shfl
            float mx = NEG_BIG;
#pragma unroll
            for (int kb = 0; kb < 4; ++kb)
                if (kb < kblim)
#pragma unroll
                    for (int r = 0; r < 4; ++r) mx = fmaxf(mx, st[kb][r]);
            mx = fmaxf(mx, __shfl_xor(mx, 16, 64));
            mx = fmaxf(mx, __shfl_xor(mx, 32, 64));
            float mn = fmaxf(m_, mx);
            float alpha = EXP2(m_ - mn);
            m_ = mn;
            float rsum = 0.f;

            // p = exp2(s - m): raw v_exp_f32 + v_perm pack (trunc), wave-private LDS
#pragma unroll
            for (int kb = 0; kb < 4; ++kb) {
                uint2 pk;
                if (kb < kblim) {
                    float p0 = EXP2(st[kb][0] - m_);
                    float p1 = EXP2(st[kb][1] - m_);
                    float p2 = EXP2(st[kb][2] - m_);
                    float p3 = EXP2(st[kb][3] - m_);
                    rsum += (p0 + p1) + (p2 + p3);
                    pk.x = pack_bf2(p0, p1);
                    pk.y = pack_bf2(p2, p3);
                } else {
                    pk.x = 0u; pk.y = 0u;
                }
                *(uint2*)(pw0 + kb * 16) = pk;
            }
            rsum += __shfl_xor(rsum, 16, 64);
            rsum += __shfl_xor(rsum, 32, 64);
            l_ = l_ * alpha + rsum;
#pragma unroll
            for (int hb = 0; hb < 4; ++hb)
#pragma unroll
                for (int r = 0; r < 4; ++r) o[hb][r] *= alpha;

            __builtin_amdgcn_s_waitcnt(0xC07F);   // lgkmcnt(0): wave-private P visible

            // O^T += Vt-tile · P : A=Vs[hd][s], B=Pl[q][s]
#pragma unroll
            for (int ks2 = 0; ks2 < 2; ++ks2) {
                bf16x8 pf = *(const bf16x8*)(&Pl[w][llo][ks2 * 32 + lhi * 8]);
#pragma unroll
                for (int hb = 0; hb < 4; ++hb) {
                    bf16x8 vf = sfrag(Vs, hb * 16 + llo, ks2 * 4 + lhi);
                    o[hb] = __builtin_amdgcn_mfma_f32_16x16x32_bf16(
                        vf, pf, o[hb], 0, 0, 0);
                }
            }
        }

        // epilogue: lane q = qt*16+llo, hd = hb*16+lhi*4+r
        u16* Cp = Ctx + (size_t)(b * 2048 + qt * 16) * 2048 + h * 64;
        float inv = __builtin_amdgcn_rcpf(l_);
#pragma unroll
        for (int hb = 0; hb < 4; ++hb) {
            short4 v;
            v.x = (short)f2bf(o[hb][0] * inv);
            v.y = (short)f2bf(o[hb][1] * inv);
            v.z = (short)f2bf(o[hb][2] * inv);
            v.w = (short)f2bf(o[hb][3] * inv);
            *(short4*)(Cp + (size_t)llo * 2048 + hb * 16 + lhi * 4) = v;
        }
    }
}

extern "C" void kernel_launch(void* const* d_in, const int* in_sizes, int n_in,
                              void* d_out, int out_size, void* d_ws, size_t ws_size,
                              hipStream_t stream) {
    const float* x  = (const float*)d_in[0];
    const float* Wq = (const float*)d_in[1];
    const float* Wk = (const float*)d_in[2];
    const float* Wv = (const float*)d_in[3];
    const float* Wo = (const float*)d_in[4];

    u16* xb  = (u16*)d_ws;
    u16* wqb = xb + 8388608;
    u16* wkb = wqb + 4194304;
    u16* wvb = wkb + 1048576;
    u16* wob = wvb + 1048576;
    u16* Kb  = wob + 4194304;
    u16* Vtb = Kb + 2097152;
    u16* Ctx = xb;               // overlay (xb dead after projections)
    u16* Qb  = (u16*)d_out;      // bf16 Q staged in fp32 out buffer
    float* out = (float*)d_out;

    cvt_all<<<dim3(9216), 256, 0, stream>>>(x, Wq, Wk, Wv, Wo, xb, wqb, wkb, wvb, wob);
    gemm_qkv<<<dim3(24, 32), 256, 0, stream>>>(xb, wqb, wkb, wvb, Qb, Kb, Vtb);
    attn6<<<dim3(64, 16), 256, 0, stream>>>(Qb, Kb, Vtb, Ctx);
    gemm_bt<<<dim3(16, 32), 256, 0, stream>>>(Ctx, wob, out, 4096, 2048, 2048);
}